// Round 8
// baseline (1604.607 us; speedup 1.0000x reference)
//
#include <hip/hip_runtime.h>
#include <math.h>

#define N_NODES 100000
#define N_EDGES 1200000
#define N_GRAPHS 256
#define CH 64
#define NC (N_NODES * CH)
#define EPS 1e-5f

#define EC (N_EDGES / 2)      // edges per pass (2 passes bound the m buffer)
#define TILES_P (EC / 64)     // 9375
#define SCAN_NB 98            // ceil((N_NODES+1)/1024)

typedef _Float16 half8 __attribute__((ext_vector_type(8)));
typedef float floatx4 __attribute__((ext_vector_type(4)));

__device__ __forceinline__ int lbound(const int* __restrict__ a, int n, int v) {
    // first i in [0,n) with a[i] >= v
    int lo = 0, hi = n;
    while (lo < hi) {
        int mid = (lo + hi) >> 1;
        if (a[mid] < v) lo = mid + 1; else hi = mid;
    }
    return lo;
}

// ---------------- embed + BN0 stats fused ----------------
__global__ void embed_stats_kernel(const float* __restrict__ x,
                                   const float* __restrict__ W,   // [12,64]
                                   const float* __restrict__ b,   // [64]
                                   float* __restrict__ out,       // [N,64]
                                   float* __restrict__ stats) {   // [128] pre-zeroed
    int c = threadIdx.x & 63;
    int sub = threadIdx.x >> 6;
    float s = 0.f, q = 0.f;
    for (int r = blockIdx.x * 4 + sub; r < N_NODES; r += gridDim.x * 4) {
        const float* xr = x + r * 12;
        float acc = b[c];
#pragma unroll
        for (int k = 0; k < 12; ++k)
            acc = fmaf(xr[k], W[k * CH + c], acc);
        out[(size_t)r * CH + c] = acc;
        s += acc;
        q = fmaf(acc, acc, q);
    }
    __shared__ float ls[4][64];
    __shared__ float lq[4][64];
    ls[sub][c] = s;
    lq[sub][c] = q;
    __syncthreads();
    if (sub == 0) {
        s = ls[0][c] + ls[1][c] + ls[2][c] + ls[3][c];
        q = lq[0][c] + lq[1][c] + lq[2][c] + lq[3][c];
        atomicAdd(&stats[c], s);
        atomicAdd(&stats[64 + c], q);
    }
}

// ---------------- BN stats ----------------
__global__ void bn_stats_kernel(const float* __restrict__ a,
                                float* __restrict__ stats) { // [128] pre-zeroed
    int c = threadIdx.x & 63;
    int sub = threadIdx.x >> 6;
    float s = 0.f, q = 0.f;
    for (int r = blockIdx.x * 4 + sub; r < N_NODES; r += gridDim.x * 4) {
        float v = a[(size_t)r * CH + c];
        s += v;
        q = fmaf(v, v, q);
    }
    __shared__ float ls[4][64];
    __shared__ float lq[4][64];
    ls[sub][c] = s;
    lq[sub][c] = q;
    __syncthreads();
    if (sub == 0) {
        s = ls[0][c] + ls[1][c] + ls[2][c] + ls[3][c];
        q = lq[0][c] + lq[1][c] + lq[2][c] + lq[3][c];
        atomicAdd(&stats[c], s);
        atomicAdd(&stats[64 + c], q);
    }
}

// ------- BN apply with fused finalize (+residual, +relu, +f16 copy) -------
template <bool RELU, bool RES, bool F16OUT>
__global__ void bn_apply_kernel(float* __restrict__ a,
                                const float* __restrict__ res,
                                const float* __restrict__ stats,
                                const float* __restrict__ gamma,
                                const float* __restrict__ beta,
                                _Float16* __restrict__ h16) {
    __shared__ float ab[128];
    if (threadIdx.x < 64) {
        int cc = threadIdx.x;
        float mean = stats[cc] * (1.0f / (float)N_NODES);
        float var  = stats[64 + cc] * (1.0f / (float)N_NODES) - mean * mean;
        float inv  = rsqrtf(var + EPS);
        float A = gamma[cc] * inv;
        ab[cc] = A;
        ab[64 + cc] = beta[cc] - mean * A;
    }
    __syncthreads();
    int idx = blockIdx.x * blockDim.x + threadIdx.x;
    if (idx >= NC) return;
    int c = idx & 63;
    float v = fmaf(a[idx], ab[c], ab[64 + c]);
    if (RES) v += res[idx];
    if (RELU) v = fmaxf(v, 0.f);
    a[idx] = v;
    if (F16OUT) h16[idx] = (_Float16)v;
}

// ---------------- counting sort of edges by dst ----------------
__global__ void hist_kernel(const int* __restrict__ ei,
                            int* __restrict__ rowptr) { // [N+1] pre-zeroed
    int e = blockIdx.x * blockDim.x + threadIdx.x;
    if (e < N_EDGES) atomicAdd(&rowptr[ei[N_EDGES + e] + 1], 1);
}

// ---- 3-phase multi-block inclusive scan over rowptr[0..N] ----
__global__ void scanA_kernel(int* __restrict__ a, int* __restrict__ btot) {
    __shared__ int wsum[16];
    int t = threadIdx.x, lane = t & 63, w = t >> 6;
    int i = blockIdx.x * 1024 + t;
    int v = (i <= N_NODES) ? a[i] : 0;
    int s = v;
#pragma unroll
    for (int d = 1; d < 64; d <<= 1) {
        int o = __shfl_up(s, d);
        if (lane >= d) s += o;
    }
    if (lane == 63) wsum[w] = s;
    __syncthreads();
    if (w == 0) {
        int ws2 = (lane < 16) ? wsum[lane] : 0;
#pragma unroll
        for (int d = 1; d < 16; d <<= 1) {
            int o = __shfl_up(ws2, d);
            if (lane >= d) ws2 += o;
        }
        if (lane < 16) wsum[lane] = ws2;
    }
    __syncthreads();
    int off = (w > 0) ? wsum[w - 1] : 0;
    if (i <= N_NODES) a[i] = s + off;
    if (t == 0) btot[blockIdx.x] = wsum[15];
}

__global__ void scanB_kernel(int* __restrict__ btot) { // 1 block, 64 threads
    int lane = threadIdx.x;
    int carry = 0;
    for (int base = 0; base < SCAN_NB; base += 64) {
        int i = base + lane;
        int v = (i < SCAN_NB) ? btot[i] : 0;
        int s = v;
#pragma unroll
        for (int d = 1; d < 64; d <<= 1) {
            int o = __shfl_up(s, d);
            if (lane >= d) s += o;
        }
        if (i < SCAN_NB) btot[i] = s + carry;
        carry += __shfl(s, 63);
    }
}

__global__ void scanC_kernel(int* __restrict__ a, const int* __restrict__ btot,
                             int* __restrict__ cursor) {
    int i = blockIdx.x * 1024 + threadIdx.x;
    int off = (blockIdx.x > 0) ? btot[blockIdx.x - 1] : 0;
    if (i <= N_NODES) {
        int val = a[i] + off;
        a[i] = val;
        if (i < N_NODES) cursor[i] = val;
    }
}

// one 8B random write per edge: sef[pos] = {src, ea_bits}
__global__ void scatter_kernel(const int* __restrict__ ei,
                               const float* __restrict__ ea,
                               int* __restrict__ cursor,
                               int2* __restrict__ sef) {
    int e = blockIdx.x * blockDim.x + threadIdx.x;
    if (e >= N_EDGES) return;
    int d = ei[N_EDGES + e];
    int pos = atomicAdd(&cursor[d], 1);
    sef[pos] = make_int2(ei[e], __float_as_int(ea[e]));
}

// sdst[pos] = d for pos in [rowptr[d], rowptr[d+1])
__global__ void fill_sdst_kernel(const int* __restrict__ rowptr,
                                 int* __restrict__ sdst) {
    int d = blockIdx.x * blockDim.x + threadIdx.x;
    if (d >= N_NODES) return;
    int s = rowptr[d], e = rowptr[d + 1];
    for (int pos = s; pos < e; ++pos) sdst[pos] = d;
}

// ---------------- weight prep: WT[n][k] = W[k][n] in f16 ----------------
__global__ void prep_weights_kernel(const float* __restrict__ Wf,  // [129,64]
                                    const float* __restrict__ Ws,  // [129,64]
                                    const float* __restrict__ bf,
                                    const float* __restrict__ bs,
                                    _Float16* __restrict__ WT,     // [128,128]
                                    float* __restrict__ w128,      // [128]
                                    float* __restrict__ bias) {    // [128]
    int idx = blockIdx.x * blockDim.x + threadIdx.x;  // 16384
    if (idx < 128 * 128) {
        int n = idx >> 7;
        int k = idx & 127;
        float v = (n < 64) ? Wf[k * 64 + n] : Ws[k * 64 + (n - 64)];
        WT[idx] = (_Float16)v;
    }
    if (idx < 128) {
        w128[idx] = (idx < 64) ? Wf[128 * 64 + idx] : Ws[128 * 64 + (idx - 64)];
        bias[idx] = (idx < 64) ? bf[idx] : bs[idx - 64];
    }
}

// ---------------- edge GEMM: barrier-free, no LDS, m -> global f16 ----------
// 256 threads = 4 waves; wave w owns cols [w*16,+16) for f AND s.
// A-frags loaded directly from global (lane(quad,l15): row=l15's node,
// k-chunk=quad*8). ea broadcast via shuffles. Writes m[e][c] f16.
__global__ __launch_bounds__(256, 4)
void gemm_m_kernel(const _Float16* __restrict__ h16, // [N,64] f16
                   const int* __restrict__ sdst,     // [E] sorted dst
                   const int2* __restrict__ sef,     // [E] {src, ea}
                   const _Float16* __restrict__ WT,  // [128,128]
                   const float* __restrict__ w128,   // [128]
                   const float* __restrict__ bias,   // [128]
                   _Float16* __restrict__ mout,      // [EC,64]
                   int E0) {
    const int t = threadIdx.x;
    const int lane = t & 63;
    const int w = t >> 6;
    const int l15 = lane & 15;
    const int quad = lane >> 4;
    const int col = w * 16 + l15;

    half8 wfr[4], wsr[4];
#pragma unroll
    for (int ks = 0; ks < 4; ++ks) {
        wfr[ks] = *(const half8*)(WT + col * 128 + ks * 32 + quad * 8);
        wsr[ks] = *(const half8*)(WT + (64 + col) * 128 + ks * 32 + quad * 8);
    }
    const float biasf = bias[col];
    const float biass = bias[64 + col];
    const float wf128v = w128[col];
    const float ws128v = w128[64 + col];

    for (int tile = blockIdx.x; tile < TILES_P; tile += gridDim.x) {
        const int base = E0 + tile * 64;

        floatx4 accf[4], accs[4];
        float eav_rt[4];
#pragma unroll
        for (int rt = 0; rt < 4; ++rt) {
#pragma unroll
            for (int r = 0; r < 4; ++r) {
                accf[rt][r] = biasf;
                accs[rt][r] = biass;
            }
        }
#pragma unroll
        for (int rt = 0; rt < 4; ++rt) {
            const int idx = base + rt * 16 + l15;
            const int drow = sdst[idx];
            const int2 sf = sef[idx];
            eav_rt[rt] = __int_as_float(sf.y);
            const _Float16* pd = h16 + (size_t)drow * CH;
            const _Float16* ps = h16 + (size_t)sf.x * CH;
            half8 a0 = *(const half8*)(pd + quad * 8);        // z k 0..31
            half8 a1 = *(const half8*)(pd + 32 + quad * 8);   // z k 32..63
            half8 a2 = *(const half8*)(ps + quad * 8);        // z k 64..95
            half8 a3 = *(const half8*)(ps + 32 + quad * 8);   // z k 96..127
            accf[rt] = __builtin_amdgcn_mfma_f32_16x16x32_f16(a0, wfr[0], accf[rt], 0, 0, 0);
            accs[rt] = __builtin_amdgcn_mfma_f32_16x16x32_f16(a0, wsr[0], accs[rt], 0, 0, 0);
            accf[rt] = __builtin_amdgcn_mfma_f32_16x16x32_f16(a1, wfr[1], accf[rt], 0, 0, 0);
            accs[rt] = __builtin_amdgcn_mfma_f32_16x16x32_f16(a1, wsr[1], accs[rt], 0, 0, 0);
            accf[rt] = __builtin_amdgcn_mfma_f32_16x16x32_f16(a2, wfr[2], accf[rt], 0, 0, 0);
            accs[rt] = __builtin_amdgcn_mfma_f32_16x16x32_f16(a2, wsr[2], accs[rt], 0, 0, 0);
            accf[rt] = __builtin_amdgcn_mfma_f32_16x16x32_f16(a3, wfr[3], accf[rt], 0, 0, 0);
            accs[rt] = __builtin_amdgcn_mfma_f32_16x16x32_f16(a3, wsr[3], accs[rt], 0, 0, 0);
        }

        // epilogue: ea rank-1 + activation + f16 store (m row-major, 64 cols)
#pragma unroll
        for (int rt = 0; rt < 4; ++rt) {
#pragma unroll
            for (int r = 0; r < 4; ++r) {
                float eav = __shfl(eav_rt[rt], quad * 4 + r);
                float f = fmaf(eav, wf128v, accf[rt][r]);
                float s = fmaf(eav, ws128v, accs[rt][r]);
                float sig = __builtin_amdgcn_rcpf(1.0f + __expf(-f));
                float sp = fmaxf(s, 0.0f) + __logf(1.0f + __expf(-fabsf(s)));
                int row = tile * 64 + rt * 16 + quad * 4 + r;  // pass-local
                mout[(size_t)row * CH + col] = (_Float16)(sig * sp);
            }
        }
    }
}

// ---------------- aggregate: node-owned walkers, plain stores ----------------
// Wave owns a contiguous node range (binary search over rowptr); lane = col.
// Sequential coalesced 128B m-row reads; per-node store (atomic only for the
// <=2 nodes clipped by a pass boundary). agg pre-zeroed (covers deg-0).
__global__ __launch_bounds__(256)
void agg_kernel(const _Float16* __restrict__ m,    // [EC,64] pass-local
                const int* __restrict__ rowptr,    // [N+1]
                float* __restrict__ agg,           // [N,64] pre-zeroed
                int E0) {
    const int E1 = E0 + EC;
    const int lane = threadIdx.x & 63;
    const int gw = (blockIdx.x * blockDim.x + threadIdx.x) >> 6;
    const int nw = (gridDim.x * 256) >> 6;

    const int e0t = E0 + (int)((long)gw * EC / nw);
    const int e1t = E0 + (int)((long)(gw + 1) * EC / nw);

    int n0;
    if (gw == 0) {
        int lb = lbound(rowptr, N_NODES + 1, E0);
        n0 = (lb > 0 && rowptr[lb] > E0) ? lb - 1 : lb;   // include straddler
    } else {
        n0 = lbound(rowptr, N_NODES + 1, e0t);
    }
    int n1 = lbound(rowptr, N_NODES + 1, e1t);

    for (int n = n0; n < n1; ++n) {
        int rs = rowptr[n], re = rowptr[n + 1];
        int es = max(rs, E0), ee = min(re, E1);
        if (ee <= es) continue;
        float acc = 0.0f;
        for (int e = es; e < ee; ++e)
            acc += (float)m[(size_t)(e - E0) * CH + lane];
        float* dp = agg + (size_t)n * CH + lane;
        if (rs < E0 || re > E1) atomicAdd(dp, acc);
        else *dp = acc;
    }
}

// ---------------- global mean pool: segmented walkers over sorted batch -----
#define POOL_BLOCKS 256
__global__ __launch_bounds__(256)
void pool_kernel(const float* __restrict__ h,
                 const int* __restrict__ batch,
                 float* __restrict__ pooled,   // [G,64] pre-zeroed
                 float* __restrict__ counts) { // [G]   pre-zeroed
    const int c = threadIdx.x & 63;
    const int walker = blockIdx.x * 4 + (threadIdx.x >> 6);
    const int nwalk = POOL_BLOCKS * 4;
    const int chunk = (N_NODES + nwalk - 1) / nwalk;
    int r0 = walker * chunk;
    int r1 = min(N_NODES, r0 + chunk);
    if (r0 >= r1) return;

    int cur = batch[r0];
    float acc = 0.0f;
    int runlen = 0;
    for (int r = r0; r < r1; ++r) {
        int b = batch[r];
        if (b != cur) {
            atomicAdd(&pooled[cur * CH + c], acc);
            if (c == 0) atomicAdd(&counts[cur], (float)runlen);
            acc = 0.0f;
            runlen = 0;
            cur = b;
        }
        acc += h[(size_t)r * CH + c];
        ++runlen;
    }
    atomicAdd(&pooled[cur * CH + c], acc);
    if (c == 0) atomicAdd(&counts[cur], (float)runlen);
}

// ---------------- head ----------------
__global__ void head_kernel(const float* __restrict__ pooled,
                            const float* __restrict__ counts,
                            const float* __restrict__ W1,
                            const float* __restrict__ b1,
                            const float* __restrict__ W2,
                            const float* __restrict__ b2,
                            float* __restrict__ out) {
    int gph = blockIdx.x;
    int t = threadIdx.x;  // 64
    __shared__ float p[64];
    __shared__ float h1[32];
    float cnt = fmaxf(counts[gph], 1.0f);
    p[t] = pooled[gph * CH + t] / cnt;
    __syncthreads();
    if (t < 32) {
        float acc = b1[t];
#pragma unroll
        for (int c = 0; c < 64; ++c)
            acc = fmaf(p[c], W1[c * 32 + t], acc);
        h1[t] = fmaxf(acc, 0.0f);
    }
    __syncthreads();
    if (t == 0) {
        float acc = b2[0];
#pragma unroll
        for (int j = 0; j < 32; ++j)
            acc = fmaf(h1[j], W2[j], acc);
        out[gph] = acc;
    }
}

extern "C" void kernel_launch(void* const* d_in, const int* in_sizes, int n_in,
                              void* d_out, int out_size, void* d_ws, size_t ws_size,
                              hipStream_t stream) {
    const float* x     = (const float*)d_in[0];
    const int*   ei    = (const int*)d_in[1];
    const float* ea    = (const float*)d_in[2];
    const int*   batch = (const int*)d_in[3];
    const float* W_in  = (const float*)d_in[4];
    const float* b_in  = (const float*)d_in[5];
    const float* g0    = (const float*)d_in[6];
    const float* beta0 = (const float*)d_in[7];

    const float* Wf[3] = {(const float*)d_in[8],  (const float*)d_in[14], (const float*)d_in[20]};
    const float* bfv[3]= {(const float*)d_in[9],  (const float*)d_in[15], (const float*)d_in[21]};
    const float* Wsv[3]= {(const float*)d_in[10], (const float*)d_in[16], (const float*)d_in[22]};
    const float* bsv[3]= {(const float*)d_in[11], (const float*)d_in[17], (const float*)d_in[23]};
    const float* gm[3] = {(const float*)d_in[12], (const float*)d_in[18], (const float*)d_in[24]};
    const float* bb[3] = {(const float*)d_in[13], (const float*)d_in[19], (const float*)d_in[25]};

    const float* W1 = (const float*)d_in[26];
    const float* b1 = (const float*)d_in[27];
    const float* W2 = (const float*)d_in[28];
    const float* b2 = (const float*)d_in[29];

    float* out = (float*)d_out;

    // ---- workspace layout (byte-based) ----
    char* base = (char*)d_ws;
    size_t off = 0;
    float* hA = (float*)(base + off);        off += (size_t)NC * 4;
    float* hB = (float*)(base + off);        off += (size_t)NC * 4;
    _Float16* h16 = (_Float16*)(base + off); off += (size_t)NC * 2;
    _Float16* WT  = (_Float16*)(base + off); off += 3 * 128 * 128 * 2;
    float* w128   = (float*)(base + off);    off += 3 * 128 * 4;
    float* biasL  = (float*)(base + off);    off += 3 * 128 * 4;
    int* cursor   = (int*)(base + off);      off += (size_t)N_NODES * 4;
    int* sdst     = (int*)(base + off);      off += (size_t)N_EDGES * 4;
    int2* sef     = (int2*)(base + off);     off += (size_t)N_EDGES * 8;
    _Float16* mbuf = (_Float16*)(base + off); off += (size_t)EC * CH * 2;  // 76.8MB
    // ---- contiguous zero-region ----
    char* zbase   = base + off;
    int* rowptr   = (int*)(base + off);      off += (size_t)(N_NODES + 1) * 4;
    int* btot     = (int*)(base + off);      off += SCAN_NB * 4;
    float* stats4 = (float*)(base + off);    off += 4 * 128 * 4;   // stats[l], l=0..3
    float* pooled = (float*)(base + off);    off += (size_t)N_GRAPHS * CH * 4;
    float* counts = (float*)(base + off);    off += (size_t)N_GRAPHS * 4;
    size_t zbytes = (size_t)(base + off - zbase);

    const int elemBlocks = (NC + 255) / 256;
    const int edgeBlocks = (N_EDGES + 255) / 256;

    hipMemsetAsync(zbase, 0, zbytes, stream);

    // ---- sort edges by dst: hist + 3-phase scan + scatter ----
    hist_kernel<<<edgeBlocks, 256, 0, stream>>>(ei, rowptr);
    scanA_kernel<<<SCAN_NB, 1024, 0, stream>>>(rowptr, btot);
    scanB_kernel<<<1, 64, 0, stream>>>(btot);
    scanC_kernel<<<SCAN_NB, 1024, 0, stream>>>(rowptr, btot, cursor);
    scatter_kernel<<<edgeBlocks, 256, 0, stream>>>(ei, ea, cursor, sef);
    fill_sdst_kernel<<<(N_NODES + 255) / 256, 256, 0, stream>>>(rowptr, sdst);

    // ---- prep f16 transposed weights ----
    for (int l = 0; l < 3; ++l)
        prep_weights_kernel<<<64, 256, 0, stream>>>(Wf[l], Wsv[l], bfv[l], bsv[l],
                                                    WT + l * 128 * 128, w128 + l * 128,
                                                    biasL + l * 128);

    // ---- input embedding + BN0 stats fused, then apply ----
    embed_stats_kernel<<<512, 256, 0, stream>>>(x, W_in, b_in, hA, stats4);
    bn_apply_kernel<true, false, true><<<elemBlocks, 256, 0, stream>>>(
        hA, nullptr, stats4, g0, beta0, h16);

    float* hcur = hA;
    float* hnext = hB;

    for (int l = 0; l < 3; ++l) {
        hipMemsetAsync(hnext, 0, (size_t)NC * sizeof(float), stream);
        for (int p = 0; p < 2; ++p) {
            gemm_m_kernel<<<2048, 256, 0, stream>>>(h16, sdst, sef,
                                                    WT + l * 128 * 128, w128 + l * 128,
                                                    biasL + l * 128, mbuf, p * EC);
            agg_kernel<<<512, 256, 0, stream>>>(mbuf, rowptr, hnext, p * EC);
        }
        float* statsL = stats4 + 128 * (l + 1);
        bn_stats_kernel<<<512, 256, 0, stream>>>(hnext, statsL);
        if (l < 2)
            bn_apply_kernel<true, true, true><<<elemBlocks, 256, 0, stream>>>(
                hnext, hcur, statsL, gm[l], bb[l], h16);
        else
            bn_apply_kernel<false, true, false><<<elemBlocks, 256, 0, stream>>>(
                hnext, hcur, statsL, gm[l], bb[l], nullptr);
        float* tmp = hcur; hcur = hnext; hnext = tmp;
    }

    // ---- pool + head ----
    pool_kernel<<<POOL_BLOCKS, 256, 0, stream>>>(hcur, batch, pooled, counts);
    head_kernel<<<N_GRAPHS, 64, 0, stream>>>(pooled, counts, W1, b1, W2, b2, out);
}

// Round 9
// 962.188 us; speedup vs baseline: 1.6677x; 1.6677x over previous
//
#include <hip/hip_runtime.h>
#include <math.h>

#define N_NODES 100000
#define N_EDGES 1200000
#define N_GRAPHS 256
#define CH 64
#define NC (N_NODES * CH)
#define EPS 1e-5f

#define EC (N_EDGES / 2)      // edges per pass (2 passes bound the m buffer)
#define TILES_P (EC / 64)     // 9375
#define SCAN_NB 98            // ceil((N_NODES+1)/1024)
#define ZSTR 136              // f16 units per Z row (128 + pad)
#define AGG_BLOCKS 2048

typedef _Float16 half8 __attribute__((ext_vector_type(8)));
typedef float floatx4 __attribute__((ext_vector_type(4)));

__device__ __forceinline__ int lbound(const int* __restrict__ a, int n, int v) {
    int lo = 0, hi = n;
    while (lo < hi) {
        int mid = (lo + hi) >> 1;
        if (a[mid] < v) lo = mid + 1; else hi = mid;
    }
    return lo;
}

// ---------------- embed + BN0 stats fused ----------------
__global__ void embed_stats_kernel(const float* __restrict__ x,
                                   const float* __restrict__ W,   // [12,64]
                                   const float* __restrict__ b,   // [64]
                                   float* __restrict__ out,       // [N,64]
                                   float* __restrict__ stats) {   // [128] pre-zeroed
    int c = threadIdx.x & 63;
    int sub = threadIdx.x >> 6;
    float s = 0.f, q = 0.f;
    for (int r = blockIdx.x * 4 + sub; r < N_NODES; r += gridDim.x * 4) {
        const float* xr = x + r * 12;
        float acc = b[c];
#pragma unroll
        for (int k = 0; k < 12; ++k)
            acc = fmaf(xr[k], W[k * CH + c], acc);
        out[(size_t)r * CH + c] = acc;
        s += acc;
        q = fmaf(acc, acc, q);
    }
    __shared__ float ls[4][64];
    __shared__ float lq[4][64];
    ls[sub][c] = s;
    lq[sub][c] = q;
    __syncthreads();
    if (sub == 0) {
        s = ls[0][c] + ls[1][c] + ls[2][c] + ls[3][c];
        q = lq[0][c] + lq[1][c] + lq[2][c] + lq[3][c];
        atomicAdd(&stats[c], s);
        atomicAdd(&stats[64 + c], q);
    }
}

// ---------------- BN stats ----------------
__global__ void bn_stats_kernel(const float* __restrict__ a,
                                float* __restrict__ stats) { // [128] pre-zeroed
    int c = threadIdx.x & 63;
    int sub = threadIdx.x >> 6;
    float s = 0.f, q = 0.f;
    for (int r = blockIdx.x * 4 + sub; r < N_NODES; r += gridDim.x * 4) {
        float v = a[(size_t)r * CH + c];
        s += v;
        q = fmaf(v, v, q);
    }
    __shared__ float ls[4][64];
    __shared__ float lq[4][64];
    ls[sub][c] = s;
    lq[sub][c] = q;
    __syncthreads();
    if (sub == 0) {
        s = ls[0][c] + ls[1][c] + ls[2][c] + ls[3][c];
        q = lq[0][c] + lq[1][c] + lq[2][c] + lq[3][c];
        atomicAdd(&stats[c], s);
        atomicAdd(&stats[64 + c], q);
    }
}

// ------- BN apply with fused finalize (+residual, +relu, +f16 copy) -------
template <bool RELU, bool RES, bool F16OUT>
__global__ void bn_apply_kernel(float* __restrict__ a,
                                const float* __restrict__ res,
                                const float* __restrict__ stats,
                                const float* __restrict__ gamma,
                                const float* __restrict__ beta,
                                _Float16* __restrict__ h16) {
    __shared__ float ab[128];
    if (threadIdx.x < 64) {
        int cc = threadIdx.x;
        float mean = stats[cc] * (1.0f / (float)N_NODES);
        float var  = stats[64 + cc] * (1.0f / (float)N_NODES) - mean * mean;
        float inv  = rsqrtf(var + EPS);
        float A = gamma[cc] * inv;
        ab[cc] = A;
        ab[64 + cc] = beta[cc] - mean * A;
    }
    __syncthreads();
    int idx = blockIdx.x * blockDim.x + threadIdx.x;
    if (idx >= NC) return;
    int c = idx & 63;
    float v = fmaf(a[idx], ab[c], ab[64 + c]);
    if (RES) v += res[idx];
    if (RELU) v = fmaxf(v, 0.f);
    a[idx] = v;
    if (F16OUT) h16[idx] = (_Float16)v;
}

// ---------------- counting sort of edges by dst ----------------
__global__ void hist_kernel(const int* __restrict__ ei,
                            int* __restrict__ rowptr) { // [N+1] pre-zeroed
    int e = blockIdx.x * blockDim.x + threadIdx.x;
    if (e < N_EDGES) atomicAdd(&rowptr[ei[N_EDGES + e] + 1], 1);
}

// ---- 3-phase multi-block inclusive scan over rowptr[0..N] ----
__global__ void scanA_kernel(int* __restrict__ a, int* __restrict__ btot) {
    __shared__ int wsum[16];
    int t = threadIdx.x, lane = t & 63, w = t >> 6;
    int i = blockIdx.x * 1024 + t;
    int v = (i <= N_NODES) ? a[i] : 0;
    int s = v;
#pragma unroll
    for (int d = 1; d < 64; d <<= 1) {
        int o = __shfl_up(s, d);
        if (lane >= d) s += o;
    }
    if (lane == 63) wsum[w] = s;
    __syncthreads();
    if (w == 0) {
        int ws2 = (lane < 16) ? wsum[lane] : 0;
#pragma unroll
        for (int d = 1; d < 16; d <<= 1) {
            int o = __shfl_up(ws2, d);
            if (lane >= d) ws2 += o;
        }
        if (lane < 16) wsum[lane] = ws2;
    }
    __syncthreads();
    int off = (w > 0) ? wsum[w - 1] : 0;
    if (i <= N_NODES) a[i] = s + off;
    if (t == 0) btot[blockIdx.x] = wsum[15];
}

__global__ void scanB_kernel(int* __restrict__ btot) { // 1 block, 64 threads
    int lane = threadIdx.x;
    int carry = 0;
    for (int base = 0; base < SCAN_NB; base += 64) {
        int i = base + lane;
        int v = (i < SCAN_NB) ? btot[i] : 0;
        int s = v;
#pragma unroll
        for (int d = 1; d < 64; d <<= 1) {
            int o = __shfl_up(s, d);
            if (lane >= d) s += o;
        }
        if (i < SCAN_NB) btot[i] = s + carry;
        carry += __shfl(s, 63);
    }
}

__global__ void scanC_kernel(int* __restrict__ a, const int* __restrict__ btot,
                             int* __restrict__ cursor) {
    int i = blockIdx.x * 1024 + threadIdx.x;
    int off = (blockIdx.x > 0) ? btot[blockIdx.x - 1] : 0;
    if (i <= N_NODES) {
        int val = a[i] + off;
        a[i] = val;
        if (i < N_NODES) cursor[i] = val;
    }
}

// one 8B random write per edge: sef[pos] = {src, ea_bits}
__global__ void scatter_kernel(const int* __restrict__ ei,
                               const float* __restrict__ ea,
                               int* __restrict__ cursor,
                               int2* __restrict__ sef) {
    int e = blockIdx.x * blockDim.x + threadIdx.x;
    if (e >= N_EDGES) return;
    int d = ei[N_EDGES + e];
    int pos = atomicAdd(&cursor[d], 1);
    sef[pos] = make_int2(ei[e], __float_as_int(ea[e]));
}

// sdst[pos] = d for pos in [rowptr[d], rowptr[d+1])
__global__ void fill_sdst_kernel(const int* __restrict__ rowptr,
                                 int* __restrict__ sdst) {
    int d = blockIdx.x * blockDim.x + threadIdx.x;
    if (d >= N_NODES) return;
    int s = rowptr[d], e = rowptr[d + 1];
    for (int pos = s; pos < e; ++pos) sdst[pos] = d;
}

// ---------------- weight prep: WT[n][k] = W[k][n] in f16 ----------------
__global__ void prep_weights_kernel(const float* __restrict__ Wf,  // [129,64]
                                    const float* __restrict__ Ws,  // [129,64]
                                    const float* __restrict__ bf,
                                    const float* __restrict__ bs,
                                    _Float16* __restrict__ WT,     // [128,128]
                                    float* __restrict__ w128,      // [128]
                                    float* __restrict__ bias) {    // [128]
    int idx = blockIdx.x * blockDim.x + threadIdx.x;  // 16384
    if (idx < 128 * 128) {
        int n = idx >> 7;
        int k = idx & 127;
        float v = (n < 64) ? Wf[k * 64 + n] : Ws[k * 64 + (n - 64)];
        WT[idx] = (_Float16)v;
    }
    if (idx < 128) {
        w128[idx] = (idx < 64) ? Wf[128 * 64 + idx] : Ws[128 * 64 + (idx - 64)];
        bias[idx] = (idx < 64) ? bf[idx] : bs[idx - 64];
    }
}

// ---------------- edge GEMM: LDS-staged Z (shared by 4 waves), m -> f16 -----
// 256 threads = 4 waves; wave w owns cols [w*16,+16) for f AND s.
// 2 barriers/tile, no aggregation machinery. Writes m[e][c] f16 to global.
__global__ __launch_bounds__(256, 4)
void gemm_m_kernel(const _Float16* __restrict__ h16, // [N,64] f16
                   const int* __restrict__ sdst,     // [E] sorted dst
                   const int2* __restrict__ sef,     // [E] {src, ea}
                   const _Float16* __restrict__ WT,  // [128,128]
                   const float* __restrict__ w128,   // [128]
                   const float* __restrict__ bias,   // [128]
                   _Float16* __restrict__ mout,      // [EC,64] pass-local
                   int E0) {
    __shared__ __align__(16) _Float16 Zs[64 * ZSTR];
    __shared__ __align__(16) float eaL[64];

    const int t = threadIdx.x;
    const int lane = t & 63;
    const int w = t >> 6;
    const int l15 = lane & 15;
    const int quad = lane >> 4;
    const int col = w * 16 + l15;

    half8 wfr[4], wsr[4];
#pragma unroll
    for (int ks = 0; ks < 4; ++ks) {
        wfr[ks] = *(const half8*)(WT + col * 128 + ks * 32 + quad * 8);
        wsr[ks] = *(const half8*)(WT + (64 + col) * 128 + ks * 32 + quad * 8);
    }
    const float biasf = bias[col];
    const float biass = bias[64 + col];
    const float wf128v = w128[col];
    const float ws128v = w128[64 + col];

    for (int tile = blockIdx.x; tile < TILES_P; tile += gridDim.x) {
        const int base = E0 + tile * 64;

        // ---- stage Z tile (4 threads/edge, 16B chunks) ----
        {
            const int e = t >> 2, q = t & 3;
            const int dst = sdst[base + e];
            const int2 sf = sef[base + e];
            const _Float16* pd = h16 + (size_t)dst * CH + q * 16;
            const _Float16* ps = h16 + (size_t)sf.x * CH + q * 16;
            half8 d0 = *(const half8*)(pd);
            half8 d1 = *(const half8*)(pd + 8);
            half8 s0 = *(const half8*)(ps);
            half8 s1 = *(const half8*)(ps + 8);
            *(half8*)(Zs + e * ZSTR + q * 16)          = d0;
            *(half8*)(Zs + e * ZSTR + q * 16 + 8)      = d1;
            *(half8*)(Zs + e * ZSTR + 64 + q * 16)     = s0;
            *(half8*)(Zs + e * ZSTR + 64 + q * 16 + 8) = s1;
            if (q == 0) eaL[e] = __int_as_float(sf.y);
        }
        __syncthreads();   // B1

        // ---- K-loop: 4 ks x 4 rt x 2 MFMA ----
        floatx4 accf[4], accs[4];
#pragma unroll
        for (int rt = 0; rt < 4; ++rt) {
#pragma unroll
            for (int r = 0; r < 4; ++r) {
                accf[rt][r] = biasf;
                accs[rt][r] = biass;
            }
        }
#pragma unroll
        for (int ks = 0; ks < 4; ++ks) {
#pragma unroll
            for (int rt = 0; rt < 4; ++rt) {
                half8 a = *(const half8*)(Zs + (rt * 16 + l15) * ZSTR + ks * 32 + quad * 8);
                accf[rt] = __builtin_amdgcn_mfma_f32_16x16x32_f16(a, wfr[ks], accf[rt], 0, 0, 0);
                accs[rt] = __builtin_amdgcn_mfma_f32_16x16x32_f16(a, wsr[ks], accs[rt], 0, 0, 0);
            }
        }

        // ---- epilogue: ea rank-1 + activation + f16 store ----
#pragma unroll
        for (int rt = 0; rt < 4; ++rt) {
            const int row0 = rt * 16 + quad * 4;
            float4 ea4 = *(const float4*)(eaL + row0);
            float eav[4] = {ea4.x, ea4.y, ea4.z, ea4.w};
#pragma unroll
            for (int r = 0; r < 4; ++r) {
                float f = fmaf(eav[r], wf128v, accf[rt][r]);
                float s = fmaf(eav[r], ws128v, accs[rt][r]);
                float sig = __builtin_amdgcn_rcpf(1.0f + __expf(-f));
                float sp = fmaxf(s, 0.0f) + __logf(1.0f + __expf(-fabsf(s)));
                int row = tile * 64 + row0 + r;  // pass-local
                mout[(size_t)row * CH + col] = (_Float16)(sig * sp);
            }
        }
        __syncthreads();   // B2 (eaL/Zs reads done before restage)
    }
}

// ---------------- aggregate: node-owned walkers, writes EVERY node ----------
// Wave owns a contiguous node range (binary search over rowptr); lane = col.
// 4 partial accumulators break the dependent-add chain. Plain store when
// rs >= E0 (incl. zeros for deg-0 nodes); atomicAdd only for the single
// pass-straddling node (rs < E0). No hnext memset needed.
__global__ __launch_bounds__(256)
void agg_kernel(const _Float16* __restrict__ m,    // [EC,64] pass-local
                const int* __restrict__ rowptr,    // [N+1]
                float* __restrict__ agg,           // [N,64]
                int E0) {
    const int E1 = E0 + EC;
    const int lane = threadIdx.x & 63;
    const int gw = (blockIdx.x * blockDim.x + threadIdx.x) >> 6;
    const int nw = (AGG_BLOCKS * 256) >> 6;

    const int e0t = E0 + (int)((long)gw * EC / nw);
    const int e1t = E0 + (int)((long)(gw + 1) * EC / nw);

    int n0;
    if (gw == 0) {
        int lb = lbound(rowptr, N_NODES + 1, E0);
        n0 = (lb > 0 && rowptr[lb] > E0) ? lb - 1 : lb;   // include straddler
    } else {
        n0 = lbound(rowptr, N_NODES + 1, e0t);
    }
    int n1 = lbound(rowptr, N_NODES + 1, e1t);

    for (int n = n0; n < n1; ++n) {
        int rs = rowptr[n], re = rowptr[n + 1];
        int es = max(rs, E0), ee = min(re, E1);
        float* dp = agg + (size_t)n * CH + lane;
        if (ee <= es) {
            if (rs >= E0) *dp = 0.0f;   // deg-0 node owned by this pass
            continue;
        }
        float a0 = 0.f, a1 = 0.f, a2 = 0.f, a3 = 0.f;
        int e = es;
        for (; e + 4 <= ee; e += 4) {
            const _Float16* mp = m + (size_t)(e - E0) * CH + lane;
            a0 += (float)mp[0];
            a1 += (float)mp[CH];
            a2 += (float)mp[2 * CH];
            a3 += (float)mp[3 * CH];
        }
        for (; e < ee; ++e)
            a0 += (float)m[(size_t)(e - E0) * CH + lane];
        float acc = (a0 + a1) + (a2 + a3);
        if (rs < E0) atomicAdd(dp, acc);   // pass-straddler: add to pass-0 part
        else *dp = acc;                    // full (or pass-0 partial) sum
    }
}

// ---------------- global mean pool: segmented walkers over sorted batch -----
#define POOL_BLOCKS 256
__global__ __launch_bounds__(256)
void pool_kernel(const float* __restrict__ h,
                 const int* __restrict__ batch,
                 float* __restrict__ pooled,   // [G,64] pre-zeroed
                 float* __restrict__ counts) { // [G]   pre-zeroed
    const int c = threadIdx.x & 63;
    const int walker = blockIdx.x * 4 + (threadIdx.x >> 6);
    const int nwalk = POOL_BLOCKS * 4;
    const int chunk = (N_NODES + nwalk - 1) / nwalk;
    int r0 = walker * chunk;
    int r1 = min(N_NODES, r0 + chunk);
    if (r0 >= r1) return;

    int cur = batch[r0];
    float acc = 0.0f;
    int runlen = 0;
    for (int r = r0; r < r1; ++r) {
        int b = batch[r];
        if (b != cur) {
            atomicAdd(&pooled[cur * CH + c], acc);
            if (c == 0) atomicAdd(&counts[cur], (float)runlen);
            acc = 0.0f;
            runlen = 0;
            cur = b;
        }
        acc += h[(size_t)r * CH + c];
        ++runlen;
    }
    atomicAdd(&pooled[cur * CH + c], acc);
    if (c == 0) atomicAdd(&counts[cur], (float)runlen);
}

// ---------------- head ----------------
__global__ void head_kernel(const float* __restrict__ pooled,
                            const float* __restrict__ counts,
                            const float* __restrict__ W1,
                            const float* __restrict__ b1,
                            const float* __restrict__ W2,
                            const float* __restrict__ b2,
                            float* __restrict__ out) {
    int gph = blockIdx.x;
    int t = threadIdx.x;  // 64
    __shared__ float p[64];
    __shared__ float h1[32];
    float cnt = fmaxf(counts[gph], 1.0f);
    p[t] = pooled[gph * CH + t] / cnt;
    __syncthreads();
    if (t < 32) {
        float acc = b1[t];
#pragma unroll
        for (int c = 0; c < 64; ++c)
            acc = fmaf(p[c], W1[c * 32 + t], acc);
        h1[t] = fmaxf(acc, 0.0f);
    }
    __syncthreads();
    if (t == 0) {
        float acc = b2[0];
#pragma unroll
        for (int j = 0; j < 32; ++j)
            acc = fmaf(h1[j], W2[j], acc);
        out[gph] = acc;
    }
}

extern "C" void kernel_launch(void* const* d_in, const int* in_sizes, int n_in,
                              void* d_out, int out_size, void* d_ws, size_t ws_size,
                              hipStream_t stream) {
    const float* x     = (const float*)d_in[0];
    const int*   ei    = (const int*)d_in[1];
    const float* ea    = (const float*)d_in[2];
    const int*   batch = (const int*)d_in[3];
    const float* W_in  = (const float*)d_in[4];
    const float* b_in  = (const float*)d_in[5];
    const float* g0    = (const float*)d_in[6];
    const float* beta0 = (const float*)d_in[7];

    const float* Wf[3] = {(const float*)d_in[8],  (const float*)d_in[14], (const float*)d_in[20]};
    const float* bfv[3]= {(const float*)d_in[9],  (const float*)d_in[15], (const float*)d_in[21]};
    const float* Wsv[3]= {(const float*)d_in[10], (const float*)d_in[16], (const float*)d_in[22]};
    const float* bsv[3]= {(const float*)d_in[11], (const float*)d_in[17], (const float*)d_in[23]};
    const float* gm[3] = {(const float*)d_in[12], (const float*)d_in[18], (const float*)d_in[24]};
    const float* bb[3] = {(const float*)d_in[13], (const float*)d_in[19], (const float*)d_in[25]};

    const float* W1 = (const float*)d_in[26];
    const float* b1 = (const float*)d_in[27];
    const float* W2 = (const float*)d_in[28];
    const float* b2 = (const float*)d_in[29];

    float* out = (float*)d_out;

    // ---- workspace layout (byte-based) ----
    char* base = (char*)d_ws;
    size_t off = 0;
    float* hA = (float*)(base + off);        off += (size_t)NC * 4;
    float* hB = (float*)(base + off);        off += (size_t)NC * 4;
    _Float16* h16 = (_Float16*)(base + off); off += (size_t)NC * 2;
    _Float16* WT  = (_Float16*)(base + off); off += 3 * 128 * 128 * 2;
    float* w128   = (float*)(base + off);    off += 3 * 128 * 4;
    float* biasL  = (float*)(base + off);    off += 3 * 128 * 4;
    int* cursor   = (int*)(base + off);      off += (size_t)N_NODES * 4;
    int* sdst     = (int*)(base + off);      off += (size_t)N_EDGES * 4;
    int2* sef     = (int2*)(base + off);     off += (size_t)N_EDGES * 8;
    _Float16* mbuf = (_Float16*)(base + off); off += (size_t)EC * CH * 2;  // 76.8MB
    // ---- contiguous zero-region ----
    char* zbase   = base + off;
    int* rowptr   = (int*)(base + off);      off += (size_t)(N_NODES + 1) * 4;
    int* btot     = (int*)(base + off);      off += SCAN_NB * 4;
    float* stats4 = (float*)(base + off);    off += 4 * 128 * 4;   // stats[l], l=0..3
    float* pooled = (float*)(base + off);    off += (size_t)N_GRAPHS * CH * 4;
    float* counts = (float*)(base + off);    off += (size_t)N_GRAPHS * 4;
    size_t zbytes = (size_t)(base + off - zbase);

    const int elemBlocks = (NC + 255) / 256;
    const int edgeBlocks = (N_EDGES + 255) / 256;

    hipMemsetAsync(zbase, 0, zbytes, stream);

    // ---- sort edges by dst: hist + 3-phase scan + scatter ----
    hist_kernel<<<edgeBlocks, 256, 0, stream>>>(ei, rowptr);
    scanA_kernel<<<SCAN_NB, 1024, 0, stream>>>(rowptr, btot);
    scanB_kernel<<<1, 64, 0, stream>>>(btot);
    scanC_kernel<<<SCAN_NB, 1024, 0, stream>>>(rowptr, btot, cursor);
    scatter_kernel<<<edgeBlocks, 256, 0, stream>>>(ei, ea, cursor, sef);
    fill_sdst_kernel<<<(N_NODES + 255) / 256, 256, 0, stream>>>(rowptr, sdst);

    // ---- prep f16 transposed weights ----
    for (int l = 0; l < 3; ++l)
        prep_weights_kernel<<<64, 256, 0, stream>>>(Wf[l], Wsv[l], bfv[l], bsv[l],
                                                    WT + l * 128 * 128, w128 + l * 128,
                                                    biasL + l * 128);

    // ---- input embedding + BN0 stats fused, then apply ----
    embed_stats_kernel<<<512, 256, 0, stream>>>(x, W_in, b_in, hA, stats4);
    bn_apply_kernel<true, false, true><<<elemBlocks, 256, 0, stream>>>(
        hA, nullptr, stats4, g0, beta0, h16);

    float* hcur = hA;
    float* hnext = hB;

    for (int l = 0; l < 3; ++l) {
        for (int p = 0; p < 2; ++p) {
            gemm_m_kernel<<<4096, 256, 0, stream>>>(h16, sdst, sef,
                                                    WT + l * 128 * 128, w128 + l * 128,
                                                    biasL + l * 128, mbuf, p * EC);
            agg_kernel<<<AGG_BLOCKS, 256, 0, stream>>>(mbuf, rowptr, hnext, p * EC);
        }
        float* statsL = stats4 + 128 * (l + 1);
        bn_stats_kernel<<<512, 256, 0, stream>>>(hnext, statsL);
        if (l < 2)
            bn_apply_kernel<true, true, true><<<elemBlocks, 256, 0, stream>>>(
                hnext, hcur, statsL, gm[l], bb[l], h16);
        else
            bn_apply_kernel<false, true, false><<<elemBlocks, 256, 0, stream>>>(
                hnext, hcur, statsL, gm[l], bb[l], nullptr);
        float* tmp = hcur; hcur = hnext; hnext = tmp;
    }

    // ---- pool + head ----
    pool_kernel<<<POOL_BLOCKS, 256, 0, stream>>>(hcur, batch, pooled, counts);
    head_kernel<<<N_GRAPHS, 64, 0, stream>>>(pooled, counts, W1, b1, W2, b2, out);
}

// Round 10
// 923.894 us; speedup vs baseline: 1.7368x; 1.0414x over previous
//
#include <hip/hip_runtime.h>
#include <math.h>

#define N_NODES 100000
#define N_EDGES 1200000
#define N_GRAPHS 256
#define CH 64
#define NC (N_NODES * CH)
#define EPS 1e-5f

#define SCAN_NB 98            // ceil((N_NODES+1)/1024)
#define ZSTRN 72              // f16 stride for node-GEMM A tile
#define GTILES ((N_NODES + 63) / 64)
#define EA_BLOCKS 2048

typedef _Float16 half8 __attribute__((ext_vector_type(8)));
typedef float floatx4 __attribute__((ext_vector_type(4)));

__device__ __forceinline__ int lbound(const int* __restrict__ a, int n, int v) {
    int lo = 0, hi = n;
    while (lo < hi) {
        int mid = (lo + hi) >> 1;
        if (a[mid] < v) lo = mid + 1; else hi = mid;
    }
    return lo;
}

// ---------------- embed + BN0 stats fused ----------------
__global__ void embed_stats_kernel(const float* __restrict__ x,
                                   const float* __restrict__ W,   // [12,64]
                                   const float* __restrict__ b,   // [64]
                                   float* __restrict__ out,       // [N,64]
                                   float* __restrict__ stats) {   // [128] pre-zeroed
    int c = threadIdx.x & 63;
    int sub = threadIdx.x >> 6;
    float s = 0.f, q = 0.f;
    for (int r = blockIdx.x * 4 + sub; r < N_NODES; r += gridDim.x * 4) {
        const float* xr = x + r * 12;
        float acc = b[c];
#pragma unroll
        for (int k = 0; k < 12; ++k)
            acc = fmaf(xr[k], W[k * CH + c], acc);
        out[(size_t)r * CH + c] = acc;
        s += acc;
        q = fmaf(acc, acc, q);
    }
    __shared__ float ls[4][64];
    __shared__ float lq[4][64];
    ls[sub][c] = s;
    lq[sub][c] = q;
    __syncthreads();
    if (sub == 0) {
        s = ls[0][c] + ls[1][c] + ls[2][c] + ls[3][c];
        q = lq[0][c] + lq[1][c] + lq[2][c] + lq[3][c];
        atomicAdd(&stats[c], s);
        atomicAdd(&stats[64 + c], q);
    }
}

// ---------------- BN stats ----------------
__global__ void bn_stats_kernel(const float* __restrict__ a,
                                float* __restrict__ stats) { // [128] pre-zeroed
    int c = threadIdx.x & 63;
    int sub = threadIdx.x >> 6;
    float s = 0.f, q = 0.f;
    for (int r = blockIdx.x * 4 + sub; r < N_NODES; r += gridDim.x * 4) {
        float v = a[(size_t)r * CH + c];
        s += v;
        q = fmaf(v, v, q);
    }
    __shared__ float ls[4][64];
    __shared__ float lq[4][64];
    ls[sub][c] = s;
    lq[sub][c] = q;
    __syncthreads();
    if (sub == 0) {
        s = ls[0][c] + ls[1][c] + ls[2][c] + ls[3][c];
        q = lq[0][c] + lq[1][c] + lq[2][c] + lq[3][c];
        atomicAdd(&stats[c], s);
        atomicAdd(&stats[64 + c], q);
    }
}

// ------- BN apply with fused finalize (+residual, +relu, +f16 copy) -------
template <bool RELU, bool RES, bool F16OUT>
__global__ void bn_apply_kernel(float* __restrict__ a,
                                const float* __restrict__ res,
                                const float* __restrict__ stats,
                                const float* __restrict__ gamma,
                                const float* __restrict__ beta,
                                _Float16* __restrict__ h16) {
    __shared__ float ab[128];
    if (threadIdx.x < 64) {
        int cc = threadIdx.x;
        float mean = stats[cc] * (1.0f / (float)N_NODES);
        float var  = stats[64 + cc] * (1.0f / (float)N_NODES) - mean * mean;
        float inv  = rsqrtf(var + EPS);
        float A = gamma[cc] * inv;
        ab[cc] = A;
        ab[64 + cc] = beta[cc] - mean * A;
    }
    __syncthreads();
    int idx = blockIdx.x * blockDim.x + threadIdx.x;
    if (idx >= NC) return;
    int c = idx & 63;
    float v = fmaf(a[idx], ab[c], ab[64 + c]);
    if (RES) v += res[idx];
    if (RELU) v = fmaxf(v, 0.f);
    a[idx] = v;
    if (F16OUT) h16[idx] = (_Float16)v;
}

// ---------------- counting sort of edges by dst ----------------
__global__ void hist_kernel(const int* __restrict__ ei,
                            int* __restrict__ rowptr) { // [N+1] pre-zeroed
    int e = blockIdx.x * blockDim.x + threadIdx.x;
    if (e < N_EDGES) atomicAdd(&rowptr[ei[N_EDGES + e] + 1], 1);
}

// ---- 3-phase multi-block inclusive scan over rowptr[0..N] ----
__global__ void scanA_kernel(int* __restrict__ a, int* __restrict__ btot) {
    __shared__ int wsum[16];
    int t = threadIdx.x, lane = t & 63, w = t >> 6;
    int i = blockIdx.x * 1024 + t;
    int v = (i <= N_NODES) ? a[i] : 0;
    int s = v;
#pragma unroll
    for (int d = 1; d < 64; d <<= 1) {
        int o = __shfl_up(s, d);
        if (lane >= d) s += o;
    }
    if (lane == 63) wsum[w] = s;
    __syncthreads();
    if (w == 0) {
        int ws2 = (lane < 16) ? wsum[lane] : 0;
#pragma unroll
        for (int d = 1; d < 16; d <<= 1) {
            int o = __shfl_up(ws2, d);
            if (lane >= d) ws2 += o;
        }
        if (lane < 16) wsum[lane] = ws2;
    }
    __syncthreads();
    int off = (w > 0) ? wsum[w - 1] : 0;
    if (i <= N_NODES) a[i] = s + off;
    if (t == 0) btot[blockIdx.x] = wsum[15];
}

__global__ void scanB_kernel(int* __restrict__ btot) { // 1 block, 64 threads
    int lane = threadIdx.x;
    int carry = 0;
    for (int base = 0; base < SCAN_NB; base += 64) {
        int i = base + lane;
        int v = (i < SCAN_NB) ? btot[i] : 0;
        int s = v;
#pragma unroll
        for (int d = 1; d < 64; d <<= 1) {
            int o = __shfl_up(s, d);
            if (lane >= d) s += o;
        }
        if (i < SCAN_NB) btot[i] = s + carry;
        carry += __shfl(s, 63);
    }
}

__global__ void scanC_kernel(int* __restrict__ a, const int* __restrict__ btot,
                             int* __restrict__ cursor) {
    int i = blockIdx.x * 1024 + threadIdx.x;
    int off = (blockIdx.x > 0) ? btot[blockIdx.x - 1] : 0;
    if (i <= N_NODES) {
        int val = a[i] + off;
        a[i] = val;
        if (i < N_NODES) cursor[i] = val;
    }
}

// one 8B random write per edge: sef[pos] = {src, ea_bits}
__global__ void scatter_kernel(const int* __restrict__ ei,
                               const float* __restrict__ ea,
                               int* __restrict__ cursor,
                               int2* __restrict__ sef) {
    int e = blockIdx.x * blockDim.x + threadIdx.x;
    if (e >= N_EDGES) return;
    int d = ei[N_EDGES + e];
    int pos = atomicAdd(&cursor[d], 1);
    sef[pos] = make_int2(ei[e], __float_as_int(ea[e]));
}

// ---------- weight prep: WT2[cc][k] (f16, [256,64]) + w128 + bias ----------
// cc 0..63 = P (Wf rows 0..63), 64..127 = Q (Wf rows 64..127),
// 128..191 = R (Ws rows 0..63), 192..255 = S (Ws rows 64..127).
__global__ void prep_weights_kernel(const float* __restrict__ Wf,  // [129,64]
                                    const float* __restrict__ Ws,  // [129,64]
                                    const float* __restrict__ bf,
                                    const float* __restrict__ bs,
                                    _Float16* __restrict__ WT2,    // [256,64]
                                    float* __restrict__ w128,      // [128]
                                    float* __restrict__ bias) {    // [128]
    int idx = blockIdx.x * blockDim.x + threadIdx.x;  // 16384
    if (idx < 256 * 64) {
        int cc = idx >> 6;
        int k = idx & 63;
        float v;
        if (cc < 64)       v = Wf[k * 64 + cc];
        else if (cc < 128) v = Wf[(64 + k) * 64 + (cc - 64)];
        else if (cc < 192) v = Ws[k * 64 + (cc - 128)];
        else               v = Ws[(64 + k) * 64 + (cc - 192)];
        WT2[idx] = (_Float16)v;
    }
    if (idx < 128) {
        w128[idx] = (idx < 64) ? Wf[128 * 64 + idx] : Ws[128 * 64 + (idx - 64)];
        bias[idx] = (idx < 64) ? bf[idx] : bs[idx - 64];
    }
}

// ---------------- node GEMM: PQRS[n][256] = h16[n][0:64] @ Wcat -------------
// block = 256 thr = 4 waves; block does 64 rows; wave w owns cols [w*64,+64).
// K=64 (2 k-steps). A staged in LDS once; 32 MFMA per block.
__global__ __launch_bounds__(256, 4)
void node_gemm_kernel(const _Float16* __restrict__ h16,   // [N,64]
                      const _Float16* __restrict__ WT2,   // [256,64]
                      _Float16* __restrict__ pqrs) {      // [N,256]
    __shared__ __align__(16) _Float16 As[64 * ZSTRN];
    const int t = threadIdx.x;
    const int lane = t & 63;
    const int w = t >> 6;
    const int l15 = lane & 15;
    const int quad = lane >> 4;

    half8 bfr[4][2];
#pragma unroll
    for (int tt = 0; tt < 4; ++tt)
#pragma unroll
        for (int ks = 0; ks < 2; ++ks)
            bfr[tt][ks] = *(const half8*)(WT2 + (w * 64 + tt * 16 + l15) * 64 + ks * 32 + quad * 8);

    const int base = blockIdx.x * 64;
    {
        int e = t >> 2, q = t & 3;
        int row = base + e;
        if (row >= N_NODES) row = N_NODES - 1;
        const _Float16* p = h16 + (size_t)row * CH + q * 16;
        *(half8*)(As + e * ZSTRN + q * 16)     = *(const half8*)p;
        *(half8*)(As + e * ZSTRN + q * 16 + 8) = *(const half8*)(p + 8);
    }
    __syncthreads();

    floatx4 acc[4][4];   // [rt][tt]
#pragma unroll
    for (int rt = 0; rt < 4; ++rt)
#pragma unroll
        for (int tt = 0; tt < 4; ++tt)
#pragma unroll
            for (int r = 0; r < 4; ++r) acc[rt][tt][r] = 0.f;

#pragma unroll
    for (int ks = 0; ks < 2; ++ks) {
#pragma unroll
        for (int rt = 0; rt < 4; ++rt) {
            half8 a = *(const half8*)(As + (rt * 16 + l15) * ZSTRN + ks * 32 + quad * 8);
#pragma unroll
            for (int tt = 0; tt < 4; ++tt)
                acc[rt][tt] = __builtin_amdgcn_mfma_f32_16x16x32_f16(a, bfr[tt][ks], acc[rt][tt], 0, 0, 0);
        }
    }

#pragma unroll
    for (int rt = 0; rt < 4; ++rt) {
#pragma unroll
        for (int r = 0; r < 4; ++r) {
            int row = base + rt * 16 + quad * 4 + r;
            if (row < N_NODES) {
#pragma unroll
                for (int tt = 0; tt < 4; ++tt)
                    pqrs[(size_t)row * 256 + w * 64 + tt * 16 + l15] = (_Float16)acc[rt][tt][r];
            }
        }
    }
}

// ------- fused edge compute + aggregation: node-owned walkers, no atomics ---
// lane = channel. Wave owns contiguous node range (edge-balanced via lbound).
// Per edge: gather Q/S rows of src (coalesced 128B), activation, accumulate.
// One plain store per node. Covers every node (zeros for deg-0).
__global__ __launch_bounds__(256)
void edge_agg_kernel(const _Float16* __restrict__ pqrs,  // [N,256]
                     const int2* __restrict__ sef,       // [E] {src, ea}
                     const int* __restrict__ rowptr,     // [N+1]
                     const float* __restrict__ w128,     // [128]
                     const float* __restrict__ bias,     // [128]
                     float* __restrict__ agg) {          // [N,64]
    const int lane = threadIdx.x & 63;
    const int gw = (blockIdx.x * blockDim.x + threadIdx.x) >> 6;
    const int nw = (EA_BLOCKS * 256) >> 6;
    const float wfc = w128[lane], wsc = w128[64 + lane];
    const float bfc = bias[lane], bsc = bias[64 + lane];

    const int e0t = (int)((long)gw * N_EDGES / nw);
    const int e1t = (int)((long)(gw + 1) * N_EDGES / nw);
    int n0 = lbound(rowptr, N_NODES + 1, e0t);
    int n1 = (gw == nw - 1) ? N_NODES : lbound(rowptr, N_NODES + 1, e1t);

    for (int n = n0; n < n1; ++n) {
        const int rs = rowptr[n], re = rowptr[n + 1];
        const _Float16* prow = pqrs + (size_t)n * 256;
        const float fb = (float)prow[lane] + bfc;
        const float sb = (float)prow[128 + lane] + bsc;
        float acc = 0.0f;
        for (int e = rs; e < re; ++e) {
            int2 sf = sef[e];
            const _Float16* qrow = pqrs + (size_t)sf.x * 256;
            float ea = __int_as_float(sf.y);
            float f = fmaf(ea, wfc, fb + (float)qrow[64 + lane]);
            float s = fmaf(ea, wsc, sb + (float)qrow[192 + lane]);
            float sig = __builtin_amdgcn_rcpf(1.0f + __expf(-f));
            float sp  = fmaxf(s, 0.0f) + __logf(1.0f + __expf(-fabsf(s)));
            acc += sig * sp;
        }
        agg[(size_t)n * CH + lane] = acc;
    }
}

// ---------------- global mean pool: segmented walkers over sorted batch -----
#define POOL_BLOCKS 256
__global__ __launch_bounds__(256)
void pool_kernel(const float* __restrict__ h,
                 const int* __restrict__ batch,
                 float* __restrict__ pooled,   // [G,64] pre-zeroed
                 float* __restrict__ counts) { // [G]   pre-zeroed
    const int c = threadIdx.x & 63;
    const int walker = blockIdx.x * 4 + (threadIdx.x >> 6);
    const int nwalk = POOL_BLOCKS * 4;
    const int chunk = (N_NODES + nwalk - 1) / nwalk;
    int r0 = walker * chunk;
    int r1 = min(N_NODES, r0 + chunk);
    if (r0 >= r1) return;

    int cur = batch[r0];
    float acc = 0.0f;
    int runlen = 0;
    for (int r = r0; r < r1; ++r) {
        int b = batch[r];
        if (b != cur) {
            atomicAdd(&pooled[cur * CH + c], acc);
            if (c == 0) atomicAdd(&counts[cur], (float)runlen);
            acc = 0.0f;
            runlen = 0;
            cur = b;
        }
        acc += h[(size_t)r * CH + c];
        ++runlen;
    }
    atomicAdd(&pooled[cur * CH + c], acc);
    if (c == 0) atomicAdd(&counts[cur], (float)runlen);
}

// ---------------- head ----------------
__global__ void head_kernel(const float* __restrict__ pooled,
                            const float* __restrict__ counts,
                            const float* __restrict__ W1,
                            const float* __restrict__ b1,
                            const float* __restrict__ W2,
                            const float* __restrict__ b2,
                            float* __restrict__ out) {
    int gph = blockIdx.x;
    int t = threadIdx.x;  // 64
    __shared__ float p[64];
    __shared__ float h1[32];
    float cnt = fmaxf(counts[gph], 1.0f);
    p[t] = pooled[gph * CH + t] / cnt;
    __syncthreads();
    if (t < 32) {
        float acc = b1[t];
#pragma unroll
        for (int c = 0; c < 64; ++c)
            acc = fmaf(p[c], W1[c * 32 + t], acc);
        h1[t] = fmaxf(acc, 0.0f);
    }
    __syncthreads();
    if (t == 0) {
        float acc = b2[0];
#pragma unroll
        for (int j = 0; j < 32; ++j)
            acc = fmaf(h1[j], W2[j], acc);
        out[gph] = acc;
    }
}

extern "C" void kernel_launch(void* const* d_in, const int* in_sizes, int n_in,
                              void* d_out, int out_size, void* d_ws, size_t ws_size,
                              hipStream_t stream) {
    const float* x     = (const float*)d_in[0];
    const int*   ei    = (const int*)d_in[1];
    const float* ea    = (const float*)d_in[2];
    const int*   batch = (const int*)d_in[3];
    const float* W_in  = (const float*)d_in[4];
    const float* b_in  = (const float*)d_in[5];
    const float* g0    = (const float*)d_in[6];
    const float* beta0 = (const float*)d_in[7];

    const float* Wf[3] = {(const float*)d_in[8],  (const float*)d_in[14], (const float*)d_in[20]};
    const float* bfv[3]= {(const float*)d_in[9],  (const float*)d_in[15], (const float*)d_in[21]};
    const float* Wsv[3]= {(const float*)d_in[10], (const float*)d_in[16], (const float*)d_in[22]};
    const float* bsv[3]= {(const float*)d_in[11], (const float*)d_in[17], (const float*)d_in[23]};
    const float* gm[3] = {(const float*)d_in[12], (const float*)d_in[18], (const float*)d_in[24]};
    const float* bb[3] = {(const float*)d_in[13], (const float*)d_in[19], (const float*)d_in[25]};

    const float* W1 = (const float*)d_in[26];
    const float* b1 = (const float*)d_in[27];
    const float* W2 = (const float*)d_in[28];
    const float* b2 = (const float*)d_in[29];

    float* out = (float*)d_out;

    // ---- workspace layout (byte-based) ----
    char* base = (char*)d_ws;
    size_t off = 0;
    float* hA = (float*)(base + off);         off += (size_t)NC * 4;
    float* hB = (float*)(base + off);         off += (size_t)NC * 4;
    _Float16* h16 = (_Float16*)(base + off);  off += (size_t)NC * 2;
    _Float16* WT2 = (_Float16*)(base + off);  off += 3 * 256 * 64 * 2;
    float* w128   = (float*)(base + off);     off += 3 * 128 * 4;
    float* biasL  = (float*)(base + off);     off += 3 * 128 * 4;
    int* cursor   = (int*)(base + off);       off += (size_t)N_NODES * 4;
    int2* sef     = (int2*)(base + off);      off += (size_t)N_EDGES * 8;
    _Float16* pqrs = (_Float16*)(base + off); off += (size_t)N_NODES * 256 * 2; // 51.2MB
    // ---- contiguous zero-region ----
    char* zbase   = base + off;
    int* rowptr   = (int*)(base + off);       off += (size_t)(N_NODES + 1) * 4;
    int* btot     = (int*)(base + off);       off += SCAN_NB * 4;
    float* stats4 = (float*)(base + off);     off += 4 * 128 * 4;
    float* pooled = (float*)(base + off);     off += (size_t)N_GRAPHS * CH * 4;
    float* counts = (float*)(base + off);     off += (size_t)N_GRAPHS * 4;
    size_t zbytes = (size_t)(base + off - zbase);

    const int elemBlocks = (NC + 255) / 256;
    const int edgeBlocks = (N_EDGES + 255) / 256;

    hipMemsetAsync(zbase, 0, zbytes, stream);

    // ---- sort edges by dst: hist + 3-phase scan + scatter ----
    hist_kernel<<<edgeBlocks, 256, 0, stream>>>(ei, rowptr);
    scanA_kernel<<<SCAN_NB, 1024, 0, stream>>>(rowptr, btot);
    scanB_kernel<<<1, 64, 0, stream>>>(btot);
    scanC_kernel<<<SCAN_NB, 1024, 0, stream>>>(rowptr, btot, cursor);
    scatter_kernel<<<edgeBlocks, 256, 0, stream>>>(ei, ea, cursor, sef);

    // ---- prep f16 concatenated/transposed weights ----
    for (int l = 0; l < 3; ++l)
        prep_weights_kernel<<<64, 256, 0, stream>>>(Wf[l], Wsv[l], bfv[l], bsv[l],
                                                    WT2 + l * 256 * 64, w128 + l * 128,
                                                    biasL + l * 128);

    // ---- input embedding + BN0 stats fused, then apply ----
    embed_stats_kernel<<<512, 256, 0, stream>>>(x, W_in, b_in, hA, stats4);
    bn_apply_kernel<true, false, true><<<elemBlocks, 256, 0, stream>>>(
        hA, nullptr, stats4, g0, beta0, h16);

    float* hcur = hA;
    float* hnext = hB;

    for (int l = 0; l < 3; ++l) {
        node_gemm_kernel<<<GTILES, 256, 0, stream>>>(h16, WT2 + l * 256 * 64, pqrs);
        edge_agg_kernel<<<EA_BLOCKS, 256, 0, stream>>>(pqrs, sef, rowptr,
                                                       w128 + l * 128, biasL + l * 128, hnext);
        float* statsL = stats4 + 128 * (l + 1);
        bn_stats_kernel<<<512, 256, 0, stream>>>(hnext, statsL);
        if (l < 2)
            bn_apply_kernel<true, true, true><<<elemBlocks, 256, 0, stream>>>(
                hnext, hcur, statsL, gm[l], bb[l], h16);
        else
            bn_apply_kernel<false, true, false><<<elemBlocks, 256, 0, stream>>>(
                hnext, hcur, statsL, gm[l], bb[l], nullptr);
        float* tmp = hcur; hcur = hnext; hnext = tmp;
    }

    // ---- pool + head ----
    pool_kernel<<<POOL_BLOCKS, 256, 0, stream>>>(hcur, batch, pooled, counts);
    head_kernel<<<N_GRAPHS, 64, 0, stream>>>(pooled, counts, W1, b1, W2, b2, out);
}